// Round 6
// baseline (219.028 us; speedup 1.0000x reference)
//
#include <hip/hip_runtime.h>

#define DD 256   // in_dim (= 2H)
#define HH 128   // per-branch out dim
#define CC 64    // n_class
#define BB 1024
#define SS1 25
#define SS2 10
#define NN 100000

typedef __attribute__((ext_vector_type(8))) short bf16x8;
typedef __attribute__((ext_vector_type(4))) float f32x4;

__device__ inline unsigned short f2b(float x) {
    union { float f; unsigned u; } v; v.f = x;
    unsigned r = (v.u + 0x7fffu + ((v.u >> 16) & 1u)) >> 16;
    return (unsigned short)r;
}
__device__ inline float b2f(unsigned u16) {
    union { unsigned u; float f; } v; v.u = u16 << 16;
    return v.f;
}

// ---------------------------------------------------------------------------
// W prep: [Wx1 | Wn1] fp32 [256][128]x2 -> bf16, MFMA B-fragment order:
//   frag = kc*16 + nt  (kc<8, nt<16; nt<8 -> Wx cols, nt>=8 -> Wn cols)
//   Wsw[(frag*64 + lane)*8 + j] = Wcat[kc*32 + (lane>>4)*8 + j][nt*16 + (lane&15)]
// ---------------------------------------------------------------------------
__global__ __launch_bounds__(256)
void prep_w(const float* __restrict__ Wx, const float* __restrict__ Wn,
            unsigned short* __restrict__ Wsw) {
    const int t    = blockIdx.x * 256 + threadIdx.x;   // 0..8191
    const int lane = t & 63;
    const int frag = t >> 6;                           // kc*16 + nt
    const int kc = frag >> 4, nt = frag & 15;
    const int quad = lane >> 4, lr = lane & 15;
    unsigned short v[8];
#pragma unroll
    for (int j = 0; j < 8; ++j) {
        int k = kc * 32 + quad * 8 + j;
        int n = nt * 16 + lr;                          // 0..255
        float w = (n < HH) ? Wx[k * HH + n] : Wn[k * HH + (n - HH)];
        v[j] = f2b(w);
    }
    ((uint4*)Wsw)[t] = *(uint4*)v;
}

// ---------------------------------------------------------------------------
// PQ = feat @ [Wx1 | Wn1] -> bf16 [NN][256]
// v7 (FROZEN, bit-identical to round 5 — this round changes megatail only,
// for clean attribution): B-resident registers, depth-2 register prefetch,
// raw lgkmcnt-only barriers. 512 persistent blocks, 2/CU.
// ---------------------------------------------------------------------------
#define PQ_BLOCKS 512
#define PQ_TILES  (NN / 32)     // 3125, exact
#define AS 264                  // bf16 row stride (528 B)

#define PQ_ISSUE(VREG, TIDX)                                                  \
    {                                                                         \
        const float* fn_ = feat + (long)(TIDX) * 32 * DD + sc * 8;            \
        _Pragma("unroll")                                                     \
        for (int i_ = 0; i_ < 4; ++i_) {                                      \
            const float4* s_ = (const float4*)(fn_ + (long)(i_ * 8 + srow) * DD); \
            VREG[2 * i_]     = s_[0];                                         \
            VREG[2 * i_ + 1] = s_[1];                                         \
        }                                                                     \
    }

#define PQ_STEP(VREG)                                                         \
    {                                                                         \
        /* 1) convert staged regs (counted vmcnt wait here) -> sAO[0] */      \
        _Pragma("unroll")                                                     \
        for (int i_ = 0; i_ < 4; ++i_) {                                      \
            int row_ = i_ * 8 + srow;                                         \
            float4 a_ = VREG[2 * i_], b_ = VREG[2 * i_ + 1];                  \
            unsigned short w8_[8] = { f2b(a_.x), f2b(a_.y), f2b(a_.z), f2b(a_.w), \
                                      f2b(b_.x), f2b(b_.y), f2b(b_.z), f2b(b_.w) }; \
            *(uint4*)&sAO[0][row_ * AS + sc * 8] = *(uint4*)w8_;              \
        }                                                                     \
        /* 2) refill this buffer with tile+2*STRIDE */                        \
        {                                                                     \
            long t2_ = tile + 2L * PQ_BLOCKS;                                 \
            if (t2_ < PQ_TILES) PQ_ISSUE(VREG, t2_);                          \
        }                                                                     \
        /* 3) raw barrier: drain LDS only; vmcnt NOT drained */               \
        asm volatile("s_waitcnt lgkmcnt(0)" ::: "memory");                    \
        __builtin_amdgcn_s_barrier();                                         \
        /* 4) MFMA: pure LDS + resident-B */                                  \
        f32x4 acc[2][4] = {};                                                 \
        _Pragma("unroll")                                                     \
        for (int kc = 0; kc < 8; ++kc) {                                      \
            bf16x8 a0 = *(const bf16x8*)&sAO[0][(lr)      * AS + kc * 32 + quad * 8]; \
            bf16x8 a1 = *(const bf16x8*)&sAO[0][(16 + lr) * AS + kc * 32 + quad * 8]; \
            _Pragma("unroll")                                                 \
            for (int j = 0; j < 4; ++j) {                                     \
                acc[0][j] = __builtin_amdgcn_mfma_f32_16x16x32_bf16(a0, B[kc][j], acc[0][j], 0, 0, 0); \
                acc[1][j] = __builtin_amdgcn_mfma_f32_16x16x32_bf16(a1, B[kc][j], acc[1][j], 0, 0, 0); \
            }                                                                 \
        }                                                                     \
        /* 5) pack acc -> bf16 into sAO[1] (row=quad*4+r, col=lr) */          \
        _Pragma("unroll")                                                     \
        for (int rt = 0; rt < 2; ++rt)                                        \
            _Pragma("unroll")                                                 \
            for (int j = 0; j < 4; ++j) {                                     \
                int col_ = (w * 4 + j) * 16 + lr;                             \
                _Pragma("unroll")                                             \
                for (int r = 0; r < 4; ++r)                                   \
                    sAO[1][(rt * 16 + quad * 4 + r) * AS + col_] = f2b(acc[rt][j][r]); \
            }                                                                 \
        /* 6) raw barrier: pack visible; all sAO[0] reads retired */          \
        asm volatile("s_waitcnt lgkmcnt(0)" ::: "memory");                    \
        __builtin_amdgcn_s_barrier();                                         \
        /* 7) readback + coalesced store */                                   \
        _Pragma("unroll")                                                     \
        for (int i_ = 0; i_ < 4; ++i_) {                                      \
            int id_  = i_ * 256 + t;                                          \
            int row_ = id_ >> 5, ch_ = id_ & 31;                              \
            uint4 d_ = *(uint4*)&sAO[1][row_ * AS + ch_ * 8];                 \
            *(uint4*)&PQb[((long)tile * 32 + row_) * DD + ch_ * 8] = d_;      \
        }                                                                     \
    }

__global__ __launch_bounds__(256, 2)
void pq_gemm(const float* __restrict__ feat,
             const unsigned short* __restrict__ Wsw,
             unsigned short* __restrict__ PQb) {
    __shared__ unsigned short sAO[2][32 * AS];   // [0]=A stage, [1]=O stage
    const int t    = threadIdx.x;
    const int w    = t >> 6, lane = t & 63;
    const int quad = lane >> 4, lr = lane & 15;

    // ---- B prologue: 32 fragments resident for this wave's 4 col-tiles
    bf16x8 B[8][4];
#pragma unroll
    for (int kc = 0; kc < 8; ++kc)
#pragma unroll
        for (int j = 0; j < 4; ++j)
            B[kc][j] = *(const bf16x8*)&Wsw[((kc * 16 + (w * 4 + j)) * 64 + lane) * 8];

    const int srow = t >> 5, sc = t & 31;

    // ---- prologue: fill both prefetch buffers (depth 2)
    float4 va[8], vb[8];
    long tile = blockIdx.x;
    PQ_ISSUE(va, tile);
    if (tile + PQ_BLOCKS < PQ_TILES) PQ_ISSUE(vb, tile + PQ_BLOCKS);

    // every block has >= 6 tiles (3125/512), so both buffers are valid
    while (true) {
        PQ_STEP(va);
        tile += PQ_BLOCKS; if (tile >= PQ_TILES) break;
        PQ_STEP(vb);
        tile += PQ_BLOCKS; if (tile >= PQ_TILES) break;
    }
}

// ---------------------------------------------------------------------------
// megatail v5: quarter-wave gather slots.
// v4's phase A had 16 half-wave slots -> serial s-depth 2 and a 16-deep LDS
// reduce; round-5 showed occupancy alone didn't help, so the residual is
// the serial gather chains. Now:
//   * 32 QUARTER-wave slots (16 lanes, uint4 = 16 B/lane covers a full
//     128-col half-row) -> s-depth 1: all 25 s-chains in flight at once.
//   * wave-internal reduction over its 4 slots via 2x __shfl_xor (16, 32),
//     then an 8-deep cross-wave LDS reduce (was 16). sred 24.6 -> 12 KB.
//   * phases B/C unchanged from v4 (verified).
// ---------------------------------------------------------------------------
__global__ __launch_bounds__(512)
void megatail(const unsigned short* __restrict__ PQb,
              const int* __restrict__ ids0, const int* __restrict__ ids1,
              const int* __restrict__ ids2,
              const float* __restrict__ bx1, const float* __restrict__ bn1,
              const float* __restrict__ Wx2, const float* __restrict__ bx2,
              const float* __restrict__ Wn2, const float* __restrict__ bn2,
              const float* __restrict__ Wfc, const float* __restrict__ bfc,
              float* __restrict__ out) {
    __shared__ float sred[8][3 * HH];   // [wave][xs(128)|ns(128)|g0n(128)] 12KB
    __shared__ float g0L[DD];
    __shared__ float gmL[DD];
    __shared__ float FP[2][DD];         // phase-B partials
    __shared__ float FL[DD];
    __shared__ float sp[8][CC];         // phase-C partials
    const int i    = blockIdx.x;
    const int t    = threadIdx.x;                  // 0..511
    const int wv   = t >> 6, lane = t & 63;
    const int l16  = lane & 15;
    const int slot = wv * 4 + (lane >> 4);         // 0..31; s = slot
    const int c0   = l16 * 8;                      // my 8-col range

    float xs[8], ns[8], g0n[8];
#pragma unroll
    for (int k = 0; k < 8; ++k) { xs[k] = 0.f; ns[k] = 0.f; g0n[k] = 0.f; }

    // ---- phase A: one s per quarter-wave slot (uniform per 16-lane group)
    if (slot < SS1) {
        const int row = i * SS1 + slot;
        const long xr = (long)ids1[row];
        uint4 xv  = *(const uint4*)&PQb[xr * DD + c0];        // X half (8 bf16)
        uint4 nv0 = *(const uint4*)&PQb[xr * DD + HH + c0];   // N half
        int myid = ids2[row * SS2 + (l16 % SS2)];
        float pa[8];
#pragma unroll
        for (int k = 0; k < 8; ++k) pa[k] = 0.f;
#pragma unroll
        for (int j = 0; j < SS2; ++j) {
            long nr = (long)__shfl(myid, (lane & 48) + j);
            uint4 nv = *(const uint4*)&PQb[nr * DD + HH + c0];
            pa[0] += b2f(nv.x & 0xffff); pa[1] += b2f(nv.x >> 16);
            pa[2] += b2f(nv.y & 0xffff); pa[3] += b2f(nv.y >> 16);
            pa[4] += b2f(nv.z & 0xffff); pa[5] += b2f(nv.z >> 16);
            pa[6] += b2f(nv.w & 0xffff); pa[7] += b2f(nv.w >> 16);
        }
        const float4 bxa = *(const float4*)&bx1[c0];
        const float4 bxb = *(const float4*)&bx1[c0 + 4];
        const float4 bna = *(const float4*)&bn1[c0];
        const float4 bnb = *(const float4*)&bn1[c0 + 4];
        constexpr float inv2 = 1.f / SS2;
        xs[0] = fmaxf(b2f(xv.x & 0xffff) + bxa.x, 0.f);
        xs[1] = fmaxf(b2f(xv.x >> 16)    + bxa.y, 0.f);
        xs[2] = fmaxf(b2f(xv.y & 0xffff) + bxa.z, 0.f);
        xs[3] = fmaxf(b2f(xv.y >> 16)    + bxa.w, 0.f);
        xs[4] = fmaxf(b2f(xv.z & 0xffff) + bxb.x, 0.f);
        xs[5] = fmaxf(b2f(xv.z >> 16)    + bxb.y, 0.f);
        xs[6] = fmaxf(b2f(xv.w & 0xffff) + bxb.z, 0.f);
        xs[7] = fmaxf(b2f(xv.w >> 16)    + bxb.w, 0.f);
        ns[0] = fmaxf(pa[0] * inv2 + bna.x, 0.f);
        ns[1] = fmaxf(pa[1] * inv2 + bna.y, 0.f);
        ns[2] = fmaxf(pa[2] * inv2 + bna.z, 0.f);
        ns[3] = fmaxf(pa[3] * inv2 + bna.w, 0.f);
        ns[4] = fmaxf(pa[4] * inv2 + bnb.x, 0.f);
        ns[5] = fmaxf(pa[5] * inv2 + bnb.y, 0.f);
        ns[6] = fmaxf(pa[6] * inv2 + bnb.z, 0.f);
        ns[7] = fmaxf(pa[7] * inv2 + bnb.w, 0.f);
        g0n[0] = b2f(nv0.x & 0xffff); g0n[1] = b2f(nv0.x >> 16);
        g0n[2] = b2f(nv0.y & 0xffff); g0n[3] = b2f(nv0.y >> 16);
        g0n[4] = b2f(nv0.z & 0xffff); g0n[5] = b2f(nv0.z >> 16);
        g0n[6] = b2f(nv0.w & 0xffff); g0n[7] = b2f(nv0.w >> 16);
    }

    // ---- wave-internal reduce over its 4 slots (lanes l16 aligned across
    //      quarter-groups -> xor 16 then 32 sums the 4 s-contributions)
#pragma unroll
    for (int k = 0; k < 8; ++k) {
        xs[k]  += __shfl_xor(xs[k], 16);  xs[k]  += __shfl_xor(xs[k], 32);
        ns[k]  += __shfl_xor(ns[k], 16);  ns[k]  += __shfl_xor(ns[k], 32);
        g0n[k] += __shfl_xor(g0n[k], 16); g0n[k] += __shfl_xor(g0n[k], 32);
    }
    if (lane < 16) {
        *(float4*)&sred[wv][c0]              = make_float4(xs[0], xs[1], xs[2], xs[3]);
        *(float4*)&sred[wv][c0 + 4]          = make_float4(xs[4], xs[5], xs[6], xs[7]);
        *(float4*)&sred[wv][HH + c0]         = make_float4(ns[0], ns[1], ns[2], ns[3]);
        *(float4*)&sred[wv][HH + c0 + 4]     = make_float4(ns[4], ns[5], ns[6], ns[7]);
        *(float4*)&sred[wv][2 * HH + c0]     = make_float4(g0n[0], g0n[1], g0n[2], g0n[3]);
        *(float4*)&sred[wv][2 * HH + c0 + 4] = make_float4(g0n[4], g0n[5], g0n[6], g0n[7]);
    }
    __syncthreads();

    // ---- cross-wave reduce (8-deep) + g0 assembly
    if (t < 384) {
        float r = 0.f;
#pragma unroll
        for (int k = 0; k < 8; ++k) r += sred[k][t];
        if (t < 256) {
            gmL[t] = r * (1.f / SS1);               // [xs_mean | ns_mean]
        } else {
            const int c = t - 256;                  // g0 N-part
            g0L[HH + c] = fmaxf(r * (1.f / SS1) + bn1[c], 0.f);
        }
    } else {
        const int c = t - 384;                      // g0 X-part
        unsigned short u = PQb[(long)ids0[i] * DD + c];
        g0L[c] = fmaxf(b2f(u) + bx1[c], 0.f);
    }
    __syncthreads();

    // ---- phase B: F[c] = dot256(g0|gm, W2 col c) + bias; k split in halves
    {
        const int c = t & 255, h = t >> 8;         // h = 0/1 (k-half)
        const bool xhalf = (c < HH);               // wave-uniform
        const float* __restrict__ W    = xhalf ? Wx2 : Wn2;
        const float* __restrict__ srcL = xhalf ? g0L : gmL;
        const int cc = c & (HH - 1);
        float fa = 0.f;
#pragma unroll 8
        for (int k = h * 128; k < h * 128 + 128; ++k) fa += srcL[k] * W[k * HH + cc];
        FP[h][c] = fa;
    }
    __syncthreads();
    if (t < 256)
        FL[t] = FP[0][t] + FP[1][t] + ((t < HH) ? bx2[t] : bn2[t - HH]);
    __syncthreads();

    // ---- phase C: out = F @ Wfc + bfc; 8 k-groups of 32
    {
        const int col = t & (CC - 1), q = t >> 6;  // q = 0..7
        float p = 0.f;
#pragma unroll 8
        for (int k = q * 32; k < q * 32 + 32; ++k) p += FL[k] * Wfc[k * CC + col];
        sp[q][col] = p;
    }
    __syncthreads();
    if (t < CC) {
        float r = bfc[t];
#pragma unroll
        for (int q = 0; q < 8; ++q) r += sp[q][t];
        out[(long)i * CC + t] = r;
    }
}

// ---------------------------------------------------------------------------
extern "C" void kernel_launch(void* const* d_in, const int* in_sizes, int n_in,
                              void* d_out, int out_size, void* d_ws, size_t ws_size,
                              hipStream_t stream) {
    const int*   ids0 = (const int*)d_in[0];
    const int*   ids1 = (const int*)d_in[1];
    const int*   ids2 = (const int*)d_in[2];
    const float* feat = (const float*)d_in[3];
    const float* Wx1  = (const float*)d_in[4];
    const float* bx1  = (const float*)d_in[5];
    const float* Wn1  = (const float*)d_in[6];
    const float* bn1  = (const float*)d_in[7];
    const float* Wx2  = (const float*)d_in[8];
    const float* bx2  = (const float*)d_in[9];
    const float* Wn2  = (const float*)d_in[10];
    const float* bn2  = (const float*)d_in[11];
    const float* Wfc  = (const float*)d_in[12];
    const float* bfc  = (const float*)d_in[13];
    float* out = (float*)d_out;

    unsigned short* PQb = (unsigned short*)d_ws;         // 51.2 MB
    unsigned short* Wsw = PQb + (long)NN * DD;           // 128 KB

    // 1) W prep (bf16 + B-fragment swizzle of [Wx1|Wn1])
    prep_w<<<32, 256, 0, stream>>>(Wx1, Wn1, Wsw);
    // 2) PQ = feat @ [Wx1|Wn1]  (bf16)                  [100000,256]
    pq_gemm<<<PQ_BLOCKS, 256, 0, stream>>>(feat, Wsw, PQb);
    // 3) everything else, row-parallel                  [1024,64]
    megatail<<<BB, 512, 0, stream>>>(PQb, ids0, ids1, ids2, bx1, bn1,
                                     Wx2, bx2, Wn2, bn2, Wfc, bfc, out);
}